// Round 6
// baseline (405.928 us; speedup 1.0000x reference)
//
#include <hip/hip_runtime.h>
#include <hip/hip_bf16.h>

typedef unsigned short u16;
typedef __attribute__((ext_vector_type(8))) __bf16 bf16x8;
typedef __attribute__((ext_vector_type(8))) u16 u16x8;
typedef __attribute__((ext_vector_type(4))) float f32x4;

__device__ __forceinline__ u16 f2bf(float f) {
    unsigned u = __float_as_uint(f);
    u += 0x7fffu + ((u >> 16) & 1u);   // round-to-nearest-even
    return (u16)(u >> 16);
}

// ---------- kernel 0: W1 [4][256][128] fp32 -> W1A in MFMA A-frag order ----------
// frag id = h*64 + rf*8 + ks  (rf = k>>4, ks = d>>5). Within frag: lane = quad*16+l15
// holds A[m = l15 = k&15][d = ks*32 + quad*8 + j], 8 bf16 = 16B per lane.
// u16 addr = fragid*512 + (quad)*128 + l15*8 + j.
__global__ __launch_bounds__(256) void transpose_w1(const float* __restrict__ W1,
                                                    u16* __restrict__ W1A) {
    __shared__ u16 tile[64][132];   // 64 d x 128 k, padded
    const int t = threadIdx.x;
    const int h = blockIdx.x >> 2;
    const int dt = blockIdx.x & 3;
#pragma unroll
    for (int j = 0; j < 8; ++j) {
        int idx = j * 256 + t;          // 2048 float4 slots
        int r = idx >> 5;               // local d-row 0..63
        int kq = idx & 31;              // float4 col (k/4)
        float4 v = *reinterpret_cast<const float4*>(
            W1 + ((size_t)h * 256 + dt * 64 + r) * 128 + kq * 4);
        ushort4 o;
        o.x = f2bf(v.x); o.y = f2bf(v.y); o.z = f2bf(v.z); o.w = f2bf(v.w);
        *reinterpret_cast<ushort4*>(&tile[r][kq * 4]) = o;
    }
    __syncthreads();
#pragma unroll
    for (int j = 0; j < 4; ++j) {
        int idx = j * 256 + t;          // 1024 u16x8 slots
        int k = idx >> 3;               // 0..127
        int c8 = idx & 7;               // local d-octet 0..7
        u16x8 o;
#pragma unroll
        for (int e = 0; e < 8; ++e) o[e] = tile[c8 * 8 + e][k];
        // frag addr: fragid = h*64 + (k>>4)*8 + (dt*2 + (c8>>2)); quad=c8&3; l15=k&15
        size_t ua = ((size_t)(h * 64 + (k >> 4) * 8 + dt * 2 + (c8 >> 2))) * 512
                  + (size_t)(c8 & 3) * 128 + (size_t)(k & 15) * 8;
        *reinterpret_cast<u16x8*>(W1A + ua) = o;
    }
}

// ---------- kernel 1: scores[N][4] = relu(x*W1+b1)*W2 + b2 ----------
// 64-node tile, 256 thr = 4 waves; wave w = head w, wave tile 128r x 64n (8x4 frags).
// xb: x tile bf16 in B-frag order (one conversion, one barrier).
// A-frags: global(L2)->VGPR, coalesced dwordx4, pipelined 1 k-step ahead.
// K-loop has ZERO barriers.
__global__ __launch_bounds__(256, 2) void score_kernel(
        const float* __restrict__ x, const u16* __restrict__ W1A,
        const float* __restrict__ b1, const float* __restrict__ W2,
        const float* __restrict__ b2, float* __restrict__ scores, int N) {
    __shared__ u16 xb[16384];   // 32 B-frags * 64 lanes * 8 bf16 = 32 KB

    const int t = threadIdx.x;
    const int wave = t >> 6;
    const int lane = t & 63;
    const int l15 = lane & 15;
    const int quad = lane >> 4;
    const int n0 = blockIdx.x * 64;

    // ---- stage x tile -> xb (frag order), 2 rounds x 8 float4 (no spill) ----
#pragma unroll
    for (int rnd = 0; rnd < 2; ++rnd) {
        float4 v[8];
#pragma unroll
        for (int i = 0; i < 8; ++i) {
            int f = (rnd * 8 + i) * 256 + t;
            int n = f >> 6, dq = f & 63;
            int nn = n0 + n; if (nn >= N) nn = N - 1;    // safe clamp (N%64==0)
            v[i] = *reinterpret_cast<const float4*>(x + (size_t)nn * 256 + dq * 4);
        }
#pragma unroll
        for (int i = 0; i < 8; ++i) {
            int f = (rnd * 8 + i) * 256 + t;
            int n = f >> 6, dq = f & 63;
            int ks = dq >> 3, qd = (dq >> 1) & 3, j0 = (dq & 1) * 4;
            int nf = n >> 4, lr = n & 15;
            ushort4 o;
            o.x = f2bf(v[i].x); o.y = f2bf(v[i].y);
            o.z = f2bf(v[i].z); o.w = f2bf(v[i].w);
            *reinterpret_cast<ushort4*>(
                &xb[((ks * 4 + nf) * 64 + qd * 16 + lr) * 8 + j0]) = o;
        }
    }
    __syncthreads();

    // ---- K-loop: A from L2 (pipelined), B from LDS, no barriers ----
    const u16* Abase = W1A + (size_t)(wave * 64) * 512 + (size_t)lane * 8;
    f32x4 acc[8][4] = {};
    bf16x8 a[2][8];
#pragma unroll
    for (int rf = 0; rf < 8; ++rf)
        a[0][rf] = *reinterpret_cast<const bf16x8*>(Abase + (rf * 8 + 0) * 512);

#pragma unroll
    for (int ks = 0; ks < 8; ++ks) {
        const int cur = ks & 1;
        bf16x8 b[4];
#pragma unroll
        for (int nf = 0; nf < 4; ++nf)
            b[nf] = *reinterpret_cast<const bf16x8*>(
                &xb[((ks * 4 + nf) * 64 + lane) * 8]);
        if (ks < 7) {
#pragma unroll
            for (int rf = 0; rf < 8; ++rf)
                a[cur ^ 1][rf] = *reinterpret_cast<const bf16x8*>(
                    Abase + (rf * 8 + ks + 1) * 512);
        }
#pragma unroll
        for (int rf = 0; rf < 8; ++rf)
#pragma unroll
            for (int nf = 0; nf < 4; ++nf)
                acc[rf][nf] = __builtin_amdgcn_mfma_f32_16x16x32_bf16(
                    a[cur][rf], b[nf], acc[rf][nf], 0, 0, 0);
    }

    // ---- epilogue: score = sum_r relu(acc + b1)*W2, in-wave only ----
    const int h = wave;
    float4 b1v[8], w2v[8];
#pragma unroll
    for (int fr = 0; fr < 8; ++fr) {
        int rb = h * 128 + fr * 16 + quad * 4;
        b1v[fr] = *reinterpret_cast<const float4*>(b1 + rb);
        w2v[fr] = *reinterpret_cast<const float4*>(W2 + rb);
    }
    const float b2v = b2[h];
#pragma unroll
    for (int nf = 0; nf < 4; ++nf) {
        float p = 0.f;
#pragma unroll
        for (int fr = 0; fr < 8; ++fr) {
            f32x4 c = acc[fr][nf];
            p += fmaxf(c[0] + b1v[fr].x, 0.f) * w2v[fr].x
               + fmaxf(c[1] + b1v[fr].y, 0.f) * w2v[fr].y
               + fmaxf(c[2] + b1v[fr].z, 0.f) * w2v[fr].z
               + fmaxf(c[3] + b1v[fr].w, 0.f) * w2v[fr].w;
        }
        p += __shfl_xor(p, 16, 64);
        p += __shfl_xor(p, 32, 64);
        int n = n0 + nf * 16 + lane;
        if (lane < 16 && n < N)
            scores[(size_t)n * 4 + h] = p + b2v;
    }
}

// ---------- kernel 2: per-(graph,head) max and 1/sum(exp) ----------
__device__ __forceinline__ int lower_bound(const int* __restrict__ a, int n, int v) {
    int lo = 0, hi = n;
    while (lo < hi) {
        int mid = (lo + hi) >> 1;
        if (a[mid] < v) lo = mid + 1; else hi = mid;
    }
    return lo;
}

__global__ __launch_bounds__(256) void segstat_kernel(
        const float4* __restrict__ scores4, const int* __restrict__ seg,
        float4* __restrict__ mOut, float4* __restrict__ isOut, int N) {
    __shared__ float4 redm[4];
    __shared__ float4 reds[4];
    const int g = blockIdx.x;
    const int t = threadIdx.x;
    const int start = lower_bound(seg, N, g);
    const int end = lower_bound(seg, N, g + 1);

    float4 mx = make_float4(-3.4e38f, -3.4e38f, -3.4e38f, -3.4e38f);
    for (int i = start + t; i < end; i += 256) {
        float4 s = scores4[i];
        mx.x = fmaxf(mx.x, s.x); mx.y = fmaxf(mx.y, s.y);
        mx.z = fmaxf(mx.z, s.z); mx.w = fmaxf(mx.w, s.w);
    }
#pragma unroll
    for (int off = 1; off < 64; off <<= 1) {
        mx.x = fmaxf(mx.x, __shfl_xor(mx.x, off, 64));
        mx.y = fmaxf(mx.y, __shfl_xor(mx.y, off, 64));
        mx.z = fmaxf(mx.z, __shfl_xor(mx.z, off, 64));
        mx.w = fmaxf(mx.w, __shfl_xor(mx.w, off, 64));
    }
    if ((t & 63) == 0) redm[t >> 6] = mx;
    __syncthreads();
    mx = redm[0];
#pragma unroll
    for (int w = 1; w < 4; ++w) {
        mx.x = fmaxf(mx.x, redm[w].x); mx.y = fmaxf(mx.y, redm[w].y);
        mx.z = fmaxf(mx.z, redm[w].z); mx.w = fmaxf(mx.w, redm[w].w);
    }

    float4 sm = make_float4(0.f, 0.f, 0.f, 0.f);
    for (int i = start + t; i < end; i += 256) {
        float4 s = scores4[i];
        sm.x += expf(s.x - mx.x); sm.y += expf(s.y - mx.y);
        sm.z += expf(s.z - mx.z); sm.w += expf(s.w - mx.w);
    }
#pragma unroll
    for (int off = 1; off < 64; off <<= 1) {
        sm.x += __shfl_xor(sm.x, off, 64);
        sm.y += __shfl_xor(sm.y, off, 64);
        sm.z += __shfl_xor(sm.z, off, 64);
        sm.w += __shfl_xor(sm.w, off, 64);
    }
    if ((t & 63) == 0) reds[t >> 6] = sm;
    __syncthreads();
    if (t == 0) {
        float4 tot = reds[0];
        for (int w = 1; w < 4; ++w) {
            tot.x += reds[w].x; tot.y += reds[w].y;
            tot.z += reds[w].z; tot.w += reds[w].w;
        }
        bool nonempty = end > start;
        float4 m_out = nonempty ? mx : make_float4(0.f, 0.f, 0.f, 0.f);
        float4 is;
        is.x = (nonempty && tot.x > 0.f) ? 1.f / tot.x : 0.f;
        is.y = (nonempty && tot.y > 0.f) ? 1.f / tot.y : 0.f;
        is.z = (nonempty && tot.z > 0.f) ? 1.f / tot.z : 0.f;
        is.w = (nonempty && tot.w > 0.f) ? 1.f / tot.w : 0.f;
        mOut[g] = m_out;
        isOut[g] = is;
    }
}

// ---------- kernel 3: out[g][d] += avg_attn[n]*x[n][d]; 64-node strips ----------
__global__ __launch_bounds__(256) void wsum_kernel(
        const float* __restrict__ x, const float4* __restrict__ scores4,
        const int* __restrict__ seg, const float4* __restrict__ mArr,
        const float4* __restrict__ isArr, float* __restrict__ out, int N) {
    __shared__ float wl[64];
    __shared__ int gl[64];
    __shared__ unsigned long long bmask_s;
    const int t = threadIdx.x;
    const int n0 = blockIdx.x * 64;
    const int cnt = min(64, N - n0);

    if (t < 64) {                         // wave 0 exactly
        int g = -1;
        float w = 0.f;
        bool bnd = false;
        if (t < cnt) {
            int n = n0 + t;
            g = seg[n];
            float4 s = scores4[n];
            float4 m = mArr[g];
            float4 is = isArr[g];
            w = 0.25f * (expf(s.x - m.x) * is.x + expf(s.y - m.y) * is.y +
                         expf(s.z - m.z) * is.z + expf(s.w - m.w) * is.w);
            bnd = (t > 0) && (g != seg[n - 1]);
        }
        wl[t] = w;
        gl[t] = g;
        unsigned long long bm = __ballot(bnd);
        if (t == 0) bmask_s = bm;
    }
    __syncthreads();
    const unsigned long long bmask = bmask_s;

    int rs = 0;
    while (rs < cnt) {                    // wave-uniform run loop
        unsigned long long mm = (rs < 63) ? (bmask & ((~0ULL) << (rs + 1))) : 0ULL;
        int re = mm ? (__ffsll((long long)mm) - 1) : cnt;
        if (re > cnt) re = cnt;
        float acc = 0.f;
        int i = rs;
        for (; i + 8 <= re; i += 8) {
            float xv[8];
#pragma unroll
            for (int j = 0; j < 8; ++j)
                xv[j] = x[(size_t)(n0 + i + j) * 256 + t];
#pragma unroll
            for (int j = 0; j < 8; ++j) acc += wl[i + j] * xv[j];
        }
        for (; i < re; ++i) acc += wl[i] * x[(size_t)(n0 + i) * 256 + t];
        atomicAdd(&out[(size_t)gl[rs] * 256 + t], acc);
        rs = re;
    }
}

extern "C" void kernel_launch(void* const* d_in, const int* in_sizes, int n_in,
                              void* d_out, int out_size, void* d_ws, size_t ws_size,
                              hipStream_t stream) {
    const float* x  = (const float*)d_in[0];
    const int* seg  = (const int*)d_in[1];
    // d_in[2] = num_graphs scalar (G=1024, fixed by problem)
    const float* W1 = (const float*)d_in[3];
    const float* b1 = (const float*)d_in[4];
    const float* W2 = (const float*)d_in[5];
    const float* b2 = (const float*)d_in[6];
    float* out = (float*)d_out;

    const int N = in_sizes[0] / 256;     // 200000
    const int G = 1024;

    char* ws = (char*)d_ws;
    float* scores = (float*)ws;                                  // N*4 fp32 = 3.2 MB
    u16* W1A      = (u16*)(ws + (size_t)N * 16);                 // 131072 u16 = 256 KB
    float* mArr   = (float*)(ws + (size_t)N * 16 + 262144);      // G*4 fp32
    float* isArr  = mArr + (size_t)G * 4;                        // G*4 fp32

    hipMemsetAsync(d_out, 0, (size_t)G * 256 * sizeof(float), stream);
    transpose_w1<<<16, 256, 0, stream>>>(W1, W1A);
    score_kernel<<<(N + 63) / 64, 256, 0, stream>>>(x, W1A, b1, W2, b2, scores, N);
    segstat_kernel<<<G, 256, 0, stream>>>((const float4*)scores, seg,
                                          (float4*)mArr, (float4*)isArr, N);
    wsum_kernel<<<(N + 63) / 64, 256, 0, stream>>>(x, (const float4*)scores, seg,
                                                   (const float4*)mArr,
                                                   (const float4*)isArr, out, N);
}